// Round 6
// baseline (174.198 us; speedup 1.0000x reference)
//
#include <hip/hip_runtime.h>
#include <hip/hip_fp16.h>

// DiffusionConv: out = x@Tf0 + Px@(Tb0+Tb1) + P2x@(Tf1+Tb2) + P3x@Tf2
// R20: revert R19 split (regressed +9.4). Budget accounting (R17/R18/R19
// consistent with one 45us ws-poison fill in the timed region) puts each
// prop at ~29us = the elephant. Theory: serial shfl->gather->fma chains
// (one gather latency per 8-edge group, max-m divergence over 4 quarters).
// New prop: 1 node/wave, octet-per-edge, 16B/lane dwordx4 gathers, ALL
// round loads issued before any FMA (static-named regs, wave-uniform
// masked rounds), 3-step shfl_xor octet reduction. Meta = one coalesced
// 4B/lane load. Props 1-2: 256-thr blocks; prop3: 1024-thr block = 16-row
// tile + R18's verified fused MFMA gemm. scatter2/build = R18 verbatim.

#define N_NODES 50000
#define N_EDGES 800000
#define C 64
#define CAP 64          // bucket capacity; rows ~ Poisson(16), P(>64) ~ 2e-18
#define NPART 196       // partitions of 256 rows: p = r >> 8
#define CAPP 4608       // edges per partition region; mean 4096, +8 sigma
#define EPB 8192        // edges per block in scatter2
#define NEB 98          // ceil(800000/8192)
#define XH_BLOCKS 782   // ceil(800000 float4 chunks / 1024)
#define CW_BLOCKS 16    // 16384 weight elems / 1024

typedef _Float16 half8 __attribute__((ext_vector_type(8)));
typedef float f32x4 __attribute__((ext_vector_type(4)));

// Fused: blocks [0,NEB): hist+reserve+scatter; [NEB,NEB+XH): x fp32->fp16;
// [NEB+XH,..): combined weights -> fp16 transposed whc[j][co][ci]
__global__ __launch_bounds__(1024) void scatter2_kernel(
        const int* __restrict__ row, const int* __restrict__ col,
        const float* __restrict__ w, int* __restrict__ percur,
        uint2* __restrict__ pedges,
        const float* __restrict__ x, __half* __restrict__ xh,
        const float* __restrict__ tf, const float* __restrict__ tb,
        _Float16* __restrict__ whc) {
    const int tid = threadIdx.x;
    if (blockIdx.x >= NEB + XH_BLOCKS) {
        int idx = (blockIdx.x - NEB - XH_BLOCKS) * 1024 + tid;  // < 16384
        int j = idx >> 12;
        int rem = idx & 4095;   // ci*64 + co
        int ci = rem >> 6;
        int co = rem & 63;
        float v;
        if (j == 0)      v = tf[rem];                         // Tf0
        else if (j == 1) v = tb[rem] + tb[4096 + rem];        // Tb0 + Tb1
        else if (j == 2) v = tf[4096 + rem] + tb[8192 + rem]; // Tf1 + Tb2
        else             v = tf[8192 + rem];                  // Tf2
        whc[(j << 12) + (co << 6) + ci] = (_Float16)v;        // transposed
        return;
    }
    if (blockIdx.x >= NEB) {
        int i = (blockIdx.x - NEB) * 1024 + tid;
        if (i < N_NODES * C / 4) {
            float4 v = ((const float4*)x)[i];
            union { float2 f2; __half2 h2[2]; } u;
            u.h2[0] = __floats2half2_rn(v.x, v.y);
            u.h2[1] = __floats2half2_rn(v.z, v.w);
            ((float2*)xh)[i] = u.f2;
        }
        return;
    }
    __shared__ int h[NPART];
    __shared__ int cur[NPART];
    uint2 ent[8];
    int pp[8];
    if (tid < NPART) h[tid] = 0;
    __syncthreads();
    int base = blockIdx.x * EPB;
#pragma unroll
    for (int i = 0; i < 8; ++i) {
        int e = base + i * 1024 + tid;
        pp[i] = -1;
        if (e < N_EDGES) {
            int r = row[e];
            unsigned int c = (unsigned int)col[e];
            unsigned int wh = (unsigned int)__half_as_ushort(__float2half_rn(w[e]));
            ent[i] = make_uint2((c << 16) | wh, (unsigned int)(r & 255));
            pp[i] = r >> 8;
            atomicAdd(&h[pp[i]], 1);
        }
    }
    __syncthreads();
    if (tid < NPART) cur[tid] = atomicAdd(&percur[tid], h[tid]);
    __syncthreads();
#pragma unroll
    for (int i = 0; i < 8; ++i) {
        if (pp[i] >= 0) {
            int slot = atomicAdd(&cur[pp[i]], 1);
            pedges[(size_t)pp[i] * CAPP + slot] = ent[i];
        }
    }
}

// One block per partition: LDS-bin 256 rows x 64 slots, fuse dinv,
// dump only the used slot prefix per row (uint4 chunks).
__global__ __launch_bounds__(1024) void build_kernel(
        const uint2* __restrict__ pedges, const int* __restrict__ percur,
        unsigned int* __restrict__ bkt, int* __restrict__ cnt,
        float* __restrict__ dinv) {
    __shared__ unsigned int lbuck[256 * CAP];   // 64 KB
    __shared__ int lcnt[256];
    const int tid = threadIdx.x;
    const int p = blockIdx.x;
    if (tid < 256) lcnt[tid] = 0;
    __syncthreads();
    int e = min(percur[p], CAPP);
    const uint2* src = pedges + (size_t)p * CAPP;
    for (int i = tid; i < e; i += 1024) {
        uint2 en = src[i];
        int rl = (int)en.y;
        int slot = atomicAdd(&lcnt[rl], 1);
        if (slot < CAP) lbuck[(rl << 6) + slot] = en.x;
    }
    __syncthreads();
    if (tid < 256) {
        int m = min(lcnt[tid], CAP);
        int g = (p << 8) + tid;
        float sum = 0.f;
        for (int j = 0; j < m; ++j)
            sum += __half2float(__ushort_as_half(
                (unsigned short)(lbuck[(tid << 6) + j] & 0xFFFFu)));
        if (g < N_NODES) {
            cnt[g] = m;
            dinv[g] = (sum > 0.f) ? rsqrtf(sum) : 0.f;
        }
    }
    __syncthreads();
    // sparse dump: 4 threads per row, chunk = tid&3; only ceil(m/4) uint4s
    {
        int r = tid >> 2;
        int ch = tid & 3;
        int m = min(lcnt[r], CAP);
        const uint4* s4 = (const uint4*)&lbuck[r << 6];
        uint4* dst = (uint4*)(bkt + (((size_t)(p << 8) + r) << 6));
        for (int j = ch; (j << 2) < m; j += 4) dst[j] = s4[j];
    }
}

// Octet-parallel prop: 1 node per wave (NPB nodes per block). Lane = oct*8+k:
// octet handles one edge per round (8 edges/round), lane loads 16B (8 halves
// [k*8, k*8+8)) of the neighbor row. All <=8 round loads issued before any
// FMA (named regs, wave-uniform masked rounds) -> one latency shadow per
// node. 3-step shfl_xor reduces octets; oct 0 writes the 128B row.
// FIRST: decode n = w*dinv[col], write back into bkt (own slot; no race).
// FUSE_GEMM (NPB=16): rows staged in LDS (stride 72), waves 0-3 then run
// the 16x64 MFMA tile: out = xh@W0 + tA@W1 + tB@W2 + tC@W3.
template <bool FIRST, bool FUSE_GEMM, int NPB>
__global__ __launch_bounds__(NPB * 64) void prop_kernel(
        const __half* __restrict__ xin, __half* __restrict__ xout,
        const int* __restrict__ cnt, unsigned int* __restrict__ bkt,
        const float* __restrict__ dinv,
        const __half* __restrict__ x0, const __half* __restrict__ x1,
        const _Float16* __restrict__ whc, float* __restrict__ out) {
    __shared__ _Float16 tcl[16 * 72];   // used only when FUSE_GEMM (2.3KB)
    const int tid = threadIdx.x;
    const int wib = tid >> 6;           // node-in-block
    const int lane = tid & 63;
    const int oct = lane >> 3;          // 0..7: edge-slot within round
    const int k = lane & 7;             // 0..7: channel octet (8 halves)
    const int node = blockIdx.x * NPB + wib;   // < 50000 always (exact grids)
    const int m = min(cnt[node], CAP);
    const int base = node << 6;
    // per-lane meta: bucket entry 'lane' (coalesced 256B per node)
    int cl = 0;
    float nl = 0.f;
    if (lane < m) {
        unsigned int b = bkt[base + lane];
        int c = (int)(b >> 16);
        float wv = __half2float(__ushort_as_half((unsigned short)(b & 0xFFFFu)));
        if constexpr (FIRST) {
            wv *= dinv[c];
            bkt[base + lane] = ((unsigned int)c << 16) |
                (unsigned int)__half_as_ushort(__float2half_rn(wv));
        }
        cl = c << 6;                    // half-elem offset of row
        nl = wv;
    }
    const int nr = (m + 7) >> 3;        // rounds (wave-uniform)
    // issue ALL round loads first, FMA after (loads overlap in one shadow)
#define LOADR(r) \
    float nn##r = 0.f; half8 v##r = {}; \
    if (nr > r) { \
        int cc = __shfl(cl, (r << 3) + oct); \
        nn##r = __shfl(nl, (r << 3) + oct); \
        v##r = *(const half8*)(const void*)(xin + cc + (k << 3)); \
    }
    LOADR(0) LOADR(1) LOADR(2) LOADR(3) LOADR(4) LOADR(5) LOADR(6) LOADR(7)
#undef LOADR
    float acc[8] = {0.f, 0.f, 0.f, 0.f, 0.f, 0.f, 0.f, 0.f};
#define FMAR(r) \
    if (nr > r) { \
        _Pragma("unroll") \
        for (int j = 0; j < 8; ++j) acc[j] += nn##r * (float)v##r[j]; \
    }
    FMAR(0) FMAR(1) FMAR(2) FMAR(3) FMAR(4) FMAR(5) FMAR(6) FMAR(7)
#undef FMAR
    // reduce across octets (8 lanes sharing k)
#pragma unroll
    for (int j = 0; j < 8; ++j) {
        acc[j] += __shfl_xor(acc[j], 8);
        acc[j] += __shfl_xor(acc[j], 16);
        acc[j] += __shfl_xor(acc[j], 32);
    }
    const float dr = dinv[node];
    if (oct == 0) {
        half8 o;
#pragma unroll
        for (int j = 0; j < 8; ++j) o[j] = (_Float16)(dr * acc[j]);
        if constexpr (!FUSE_GEMM) {
            *(half8*)(void*)(xout + ((size_t)node << 6) + (k << 3)) = o;
        } else {
            *(half8*)(void*)&tcl[wib * 72 + (k << 3)] = o;
        }
    }
    if constexpr (FUSE_GEMM) {
        __syncthreads();
        if (tid >= 256) return;
        // ---- fused MFMA GEMM for this block's 16-row tile (R18-verified) ----
        // A-frag: A[m=lane&15][k=quad*8+i]; B-frag from transposed whc[j][n][k];
        // C/D: col=lane&15, row=quad*4+reg. Wave wv4 does cols [16*wv4, +16).
        const int wv4 = tid >> 6;
        const int lane4 = tid & 63;
        const int quad = lane4 >> 4;
        const int l16 = lane4 & 15;
        const int mbase = blockIdx.x << 4;
        const __half* gsrc[3] = {x0, x1, xin};   // xh, tA, tB
        const size_t abase = ((size_t)(mbase + l16) << 6) + (quad << 3);
        f32x4 acc2 = {};
#pragma unroll
        for (int j = 0; j < 4; ++j) {
#pragma unroll
            for (int kk = 0; kk < 64; kk += 32) {
                half8 af;
                if (j < 3)
                    af = *(const half8*)(const void*)(gsrc[j] + abase + kk);
                else
                    af = *(const half8*)(const void*)&tcl[l16 * 72 + (quad << 3) + kk];
                const _Float16* wb = whc + (j << 12) + (((wv4 << 4) + l16) << 6)
                                         + (quad << 3) + kk;
                half8 bf = *(const half8*)(const void*)wb;
                acc2 = __builtin_amdgcn_mfma_f32_16x16x32_f16(af, bf, acc2, 0, 0, 0);
            }
        }
#pragma unroll
        for (int i = 0; i < 4; ++i) {
            int r = mbase + (quad << 2) + i;
            out[((size_t)r << 6) + (wv4 << 4) + l16] = acc2[i];
        }
    }
}

extern "C" void kernel_launch(void* const* d_in, const int* in_sizes, int n_in,
                              void* d_out, int out_size, void* d_ws, size_t ws_size,
                              hipStream_t stream) {
    const float* x  = (const float*)d_in[0];
    const int*   ei = (const int*)d_in[1];   // row = ei[0..E), col = ei[E..2E)
    const float* ew = (const float*)d_in[2];
    const float* tf = (const float*)d_in[3];
    const float* tb = (const float*)d_in[4];
    float* out = (float*)d_out;

    const int* row = ei;
    const int* col = ei + N_EDGES;

    // workspace layout (4B words), total ~40 MB
    const int NROWS_PAD = NPART * 256;   // 50176
    float* ws = (float*)d_ws;
    size_t off = 0;
    int*    percur = (int*)(ws + off); off += 256;
    uint2*  pedges = (uint2*)(ws + off); off += (size_t)NPART * CAPP * 2;
    unsigned int* bkt = (unsigned int*)(ws + off); off += (size_t)NROWS_PAD * CAP;
    int*    cnt  = (int*)(ws + off); off += NROWS_PAD;
    float*  dinv = ws + off; off += NROWS_PAD;
    __half* xh   = (__half*)(ws + off); off += (size_t)N_NODES * C / 2;
    __half* tA   = (__half*)(ws + off); off += (size_t)N_NODES * C / 2;
    __half* tB   = (__half*)(ws + off); off += (size_t)N_NODES * C / 2;
    _Float16* whc = (_Float16*)(ws + off); off += 4 * 64 * 64 / 2;

    hipMemsetAsync(percur, 0, 256 * sizeof(int), stream);

    scatter2_kernel<<<NEB + XH_BLOCKS + CW_BLOCKS, 1024, 0, stream>>>(
        row, col, ew, percur, pedges, x, xh, tf, tb, whc);
    build_kernel<<<NPART, 1024, 0, stream>>>(pedges, percur, bkt, cnt, dinv);

    prop_kernel<true,  false, 4><<<12500, 256, 0, stream>>>(
        xh, tA, cnt, bkt, dinv, nullptr, nullptr, nullptr, nullptr);   // tx1
    prop_kernel<false, false, 4><<<12500, 256, 0, stream>>>(
        tA, tB, cnt, bkt, dinv, nullptr, nullptr, nullptr, nullptr);   // tx2
    prop_kernel<false, true, 16><<<3125, 1024, 0, stream>>>(
        tB, nullptr, cnt, bkt, dinv, xh, tA, whc, out);                // tx3+gemm
}